// Round 5
// baseline (30.727 us; speedup 1.0000x reference)
//
#include <hip/hip_runtime.h>

#define N_IN   4096
#define N_NPB  64
#define COLS   16384
#define BATCH  128

typedef unsigned int       uint;
typedef unsigned short     ushort;
typedef unsigned long long u64;
typedef __attribute__((ext_vector_type(2))) _Float16 h2;

// ---------------------------------------------------------------------------
// ws layout:
//   [0,      1 MiB)       xTh  : f16 xT[4096][128] (ushort)
//   [1 MiB,  1 MiB+128 K) keep : ushort[COLS][4] = 64-bit keep mask per column
// ---------------------------------------------------------------------------

// keepmask helper: bit j (of this 16-k group) = 1 iff no later k' duplicates.
template <int KBASE>
static __device__ __forceinline__ uint compute_bits(const int* __restrict__ ip) {
  int v[64 - KBASE];
#pragma unroll
  for (int k = 0; k < 64 - KBASE; ++k) v[k] = ip[(KBASE + k) * COLS];
  uint bits = 0;
#pragma unroll
  for (int j = 0; j < 16; ++j) {
    uint m = 0xffffffffu;
#pragma unroll
    for (int kp = j + 1; kp < 64 - KBASE; ++kp)
      m = min(m, (uint)(v[j] ^ v[kp]));
    bits |= (m != 0u) ? (1u << j) : 0u;
  }
  return bits;
}

// Fused prep: blocks [0,512) transpose x -> f16 xT; blocks [512,768) keepmask.
__global__ __launch_bounds__(256, 4) void prep_kernel(
    const float* __restrict__ x, const int* __restrict__ idx,
    ushort* __restrict__ xTh, ushort* __restrict__ keep16) {
  const int bid = blockIdx.x;
  const int tid = threadIdx.x;
  if (bid < 512) {
    __shared__ float tile[32][33];
    const int i0 = (bid & 127) * 32;
    const int b0 = (bid >> 7) * 32;
    const int tx = tid & 31;
    const int ty = tid >> 5;    // 0..7
#pragma unroll
    for (int j = 0; j < 32; j += 8)
      tile[ty + j][tx] = x[(b0 + ty + j) * N_IN + i0 + tx];
    __syncthreads();
#pragma unroll
    for (int j = 0; j < 32; j += 8)
      xTh[(i0 + ty + j) * BATCH + b0 + tx] =
          __builtin_bit_cast(ushort, (_Float16)tile[tx][ty + j]);
  } else {
    const int kg = __builtin_amdgcn_readfirstlane(tid >> 6);  // wave-uniform
    const int c  = (bid - 512) * 64 + (tid & 63);
    const int* ip = idx + c;
    uint bits;
    if      (kg == 0) bits = compute_bits<0>(ip);
    else if (kg == 1) bits = compute_bits<16>(ip);
    else if (kg == 2) bits = compute_bits<32>(ip);
    else              bits = compute_bits<48>(ip);
    keep16[c * 4 + kg] = (ushort)bits;
  }
}

// ---------------------------------------------------------------------------
// Main: out[b,c] = sum_k wk * xTh[idx[k][c]][b]
// Grid (COLS/16, 2): block = 16 columns x 64 batches -> 2048 blocks = 8/CU.
// 256 threads = 4 waves, 4 columns/wave: g=lane>>4 (column), b8=lane&15
// (batch quartet; one dwordx2 = 4 f16 batches). Per-(k,c) entry pre-packed
// in LDS: lo32 = idx<<8 byte offset, hi32 = duplicated f16 weight.
// ---------------------------------------------------------------------------
__global__ __launch_bounds__(256, 8) void branch_main_kernel(
    const float* __restrict__ w, const int* __restrict__ idx,
    const u64* __restrict__ keep, const ushort* __restrict__ xTh,
    float* __restrict__ out) {
  __shared__ u64   pk[N_NPB][16];
  __shared__ float res2[16][65];

  const int tid   = threadIdx.x;
  const int c0    = blockIdx.x * 16;
  const int bhalf = blockIdx.y;       // which 64-batch half

  // Stage packed (offset | dup'd f16 weight) entries; 4 per thread, coalesced.
  {
    const int cl = tid & 15;
    const int k0 = (tid >> 4) * 4;
    const u64 km = keep[c0 + cl];
#pragma unroll
    for (int p = 0; p < 4; ++p) {
      const int k   = k0 + p;
      const int row = idx[k * COLS + c0 + cl];
      float wv      = w[k * COLS + c0 + cl];
      wv = ((km >> k) & 1ull) ? wv : 0.0f;
      const uint hb = (uint)__builtin_bit_cast(ushort, (_Float16)wv);
      pk[k][cl] = ((u64)((hb << 16) | hb) << 32) | ((u64)((uint)row << 8));
    }
  }
  __syncthreads();

  const int wave = tid >> 6;
  const int lane = tid & 63;
  const int g    = lane >> 4;
  const int b8   = lane & 15;
  const int cl   = wave * 4 + g;

  // 32-bit per-lane byte offset into xTh (1 MiB) -> saddr-form global loads.
  const uint lane_base = (uint)bhalf * 128 + (uint)b8 * 8;
  const char* xb = (const char*)xTh;

  h2 a0 = (h2)0.0f, a1 = (h2)0.0f;
#pragma unroll
  for (int k = 0; k < N_NPB; ++k) {
    const u64  e    = pk[k][cl];                     // ds_read_b64, 4-way bcast
    const uint voff = (uint)e + lane_base;           // one v_add_u32
    const h2   wh   = __builtin_bit_cast(h2, (uint)(e >> 32));
    const uint2 u   = *(const uint2*)(xb + voff);    // 4 f16 batches
    a0 += __builtin_bit_cast(h2, u.x) * wh;          // v_pk_fma_f16
    a1 += __builtin_bit_cast(h2, u.y) * wh;
  }

  // Stage results: 4 consecutive floats per lane -> ds_write_b128.
  {
    float* r = &res2[cl][b8 * 4];
    r[0] = (float)a0.x; r[1] = (float)a0.y;
    r[2] = (float)a1.x; r[3] = (float)a1.y;
  }
  __syncthreads();

  // Coalesced output: 16 consecutive floats per 16-lane group.
  for (int e = tid; e < 64 * 16; e += 256) {
    const int b = e >> 4, cc = e & 15;
    out[(bhalf * 64 + b) * COLS + c0 + cc] = res2[cc][b];
  }
}

extern "C" void kernel_launch(void* const* d_in, const int* in_sizes, int n_in,
                              void* d_out, int out_size, void* d_ws, size_t ws_size,
                              hipStream_t stream) {
  const float* x   = (const float*)d_in[0];
  const float* w   = (const float*)d_in[1];
  const int*   idx = (const int*)d_in[2];
  float* out = (float*)d_out;

  char* ws = (char*)d_ws;
  ushort* xTh    = (ushort*)(ws);
  ushort* keep16 = (ushort*)(ws + (1u << 20));
  u64*    keep   = (u64*)(ws + (1u << 20));

  hipLaunchKernelGGL(prep_kernel, dim3(512 + COLS / 64), dim3(256), 0, stream,
                     x, idx, xTh, keep16);
  hipLaunchKernelGGL(branch_main_kernel, dim3(COLS / 16, 2), dim3(256), 0,
                     stream, w, idx, keep, xTh, out);
}

// Round 6
// 23.812 us; speedup vs baseline: 1.2904x; 1.2904x over previous
//
#include <hip/hip_runtime.h>

#define N_IN   4096
#define N_NPB  64
#define COLS   16384
#define BATCH  128

typedef unsigned int       uint;
typedef unsigned short     ushort;
typedef unsigned long long u64;
typedef __attribute__((ext_vector_type(2))) _Float16 h2;

// ---------------------------------------------------------------------------
// ws layout:
//   [0,      1 MiB)       xTh  : f16 xT[4096][128] (ushort)
//   [1 MiB,  1 MiB+128 K) keep : ushort[COLS][4] = 64-bit keep mask per column
// ---------------------------------------------------------------------------

// keepmask helper: bit j (of this 16-k group) = 1 iff no later k' duplicates.
template <int KBASE>
static __device__ __forceinline__ uint compute_bits(const int* __restrict__ ip) {
  int v[64 - KBASE];
#pragma unroll
  for (int k = 0; k < 64 - KBASE; ++k) v[k] = ip[(KBASE + k) * COLS];
  uint bits = 0;
#pragma unroll
  for (int j = 0; j < 16; ++j) {
    uint m = 0xffffffffu;
#pragma unroll
    for (int kp = j + 1; kp < 64 - KBASE; ++kp)
      m = min(m, (uint)(v[j] ^ v[kp]));
    bits |= (m != 0u) ? (1u << j) : 0u;
  }
  return bits;
}

// Fused prep: blocks [0,512) transpose x -> f16 xT; blocks [512,768) keepmask.
__global__ __launch_bounds__(256, 4) void prep_kernel(
    const float* __restrict__ x, const int* __restrict__ idx,
    ushort* __restrict__ xTh, ushort* __restrict__ keep16) {
  const int bid = blockIdx.x;
  const int tid = threadIdx.x;
  if (bid < 512) {
    __shared__ float tile[32][33];
    const int i0 = (bid & 127) * 32;
    const int b0 = (bid >> 7) * 32;
    const int tx = tid & 31;
    const int ty = tid >> 5;    // 0..7
#pragma unroll
    for (int j = 0; j < 32; j += 8)
      tile[ty + j][tx] = x[(b0 + ty + j) * N_IN + i0 + tx];
    __syncthreads();
#pragma unroll
    for (int j = 0; j < 32; j += 8)
      xTh[(i0 + ty + j) * BATCH + b0 + tx] =
          __builtin_bit_cast(ushort, (_Float16)tile[tx][ty + j]);
  } else {
    const int kg = __builtin_amdgcn_readfirstlane(tid >> 6);  // wave-uniform
    const int c  = (bid - 512) * 64 + (tid & 63);
    const int* ip = idx + c;
    uint bits;
    if      (kg == 0) bits = compute_bits<0>(ip);
    else if (kg == 1) bits = compute_bits<16>(ip);
    else if (kg == 2) bits = compute_bits<32>(ip);
    else              bits = compute_bits<48>(ip);
    keep16[c * 4 + kg] = (ushort)bits;
  }
}

// ---------------------------------------------------------------------------
// Main: out[b,c] = sum_k wk * xTh[idx[k][c]][b]
// Split-k: 512 threads = 8 waves. Waves 0-3 do k=0..31, waves 4-7 k=32..63,
// both for the block's 16 columns; partials combined in LDS at the end.
// Within a wave-quad: g=lane>>4 (column of 4), b8=lane&15 (batch octet,
// one dwordx4 = 8 f16 batches -> full 256 B row per 16-lane group).
// Grid 1024 -> 4 blocks/CU x 8 waves = 32 waves/CU (full occupancy).
// ---------------------------------------------------------------------------
__global__ __launch_bounds__(512, 8) void branch_main_kernel(
    const float* __restrict__ w, const int* __restrict__ idx,
    const u64* __restrict__ keep, const ushort* __restrict__ xTh,
    float* __restrict__ out) {
  __shared__ u64   pk[N_NPB][16];
  __shared__ float res[2][16][132];   // [khalf][col][batch], 132: 16B-aligned rows

  const int tid = threadIdx.x;
  const int c0  = blockIdx.x * 16;

  // Stage packed (offset | dup'd f16 weight) entries; 2 per thread, coalesced.
  {
    const int cl = tid & 15;
    const int k0 = (tid >> 4) * 2;
    const u64 km = keep[c0 + cl];
#pragma unroll
    for (int p = 0; p < 2; ++p) {
      const int k   = k0 + p;
      const int row = idx[k * COLS + c0 + cl];
      float wv      = w[k * COLS + c0 + cl];
      wv = ((km >> k) & 1ull) ? wv : 0.0f;
      const uint hb = (uint)__builtin_bit_cast(ushort, (_Float16)wv);
      pk[k][cl] = ((u64)((hb << 16) | hb) << 32) | ((u64)((uint)row << 8));
    }
  }
  __syncthreads();

  const int wave  = tid >> 6;
  const int khalf = wave >> 2;        // 0: k=0..31, 1: k=32..63
  const int lane  = tid & 63;
  const int g     = lane >> 4;
  const int b8    = lane & 15;
  const int cl    = (wave & 3) * 4 + g;

  const char* xb = (const char*)xTh;
  const uint  bo = (uint)b8 * 16;
  const int   kb = khalf * 32;

  h2 a0 = (h2)0.0f, a1 = (h2)0.0f, a2 = (h2)0.0f, a3 = (h2)0.0f;
#pragma unroll
  for (int kk = 0; kk < 32; ++kk) {
    const u64  e   = pk[kb + kk][cl];                 // ds_read_b64, broadcast
    const uint off = (uint)e + bo;                    // one v_add_u32
    const h2   wh  = __builtin_bit_cast(h2, (uint)(e >> 32));
    const uint4 u  = *(const uint4*)(xb + off);       // 8 f16 batches
    a0 += __builtin_bit_cast(h2, u.x) * wh;           // v_pk_fma_f16
    a1 += __builtin_bit_cast(h2, u.y) * wh;
    a2 += __builtin_bit_cast(h2, u.z) * wh;
    a3 += __builtin_bit_cast(h2, u.w) * wh;
  }

  // Stage partials: 8 consecutive floats per lane -> 2x ds_write_b128.
  {
    float* r = &res[khalf][cl][b8 * 8];
    r[0] = (float)a0.x; r[1] = (float)a0.y;
    r[2] = (float)a1.x; r[3] = (float)a1.y;
    r[4] = (float)a2.x; r[5] = (float)a2.y;
    r[6] = (float)a3.x; r[7] = (float)a3.y;
  }
  __syncthreads();

  // Combine split-k partials + coalesced output.
  for (int e = tid; e < BATCH * 16; e += 512) {
    const int b = e >> 4, cc = e & 15;
    out[b * COLS + c0 + cc] = res[0][cc][b] + res[1][cc][b];
  }
}

extern "C" void kernel_launch(void* const* d_in, const int* in_sizes, int n_in,
                              void* d_out, int out_size, void* d_ws, size_t ws_size,
                              hipStream_t stream) {
  const float* x   = (const float*)d_in[0];
  const float* w   = (const float*)d_in[1];
  const int*   idx = (const int*)d_in[2];
  float* out = (float*)d_out;

  char* ws = (char*)d_ws;
  ushort* xTh    = (ushort*)(ws);
  ushort* keep16 = (ushort*)(ws + (1u << 20));
  u64*    keep   = (u64*)(ws + (1u << 20));

  hipLaunchKernelGGL(prep_kernel, dim3(512 + COLS / 64), dim3(256), 0, stream,
                     x, idx, xTh, keep16);
  hipLaunchKernelGGL(branch_main_kernel, dim3(COLS / 16), dim3(512), 0, stream,
                     w, idx, keep, xTh, out);
}